// Round 4
// baseline (451.677 us; speedup 1.0000x reference)
//
#include <hip/hip_runtime.h>
#include <stdint.h>

// ---------------------------------------------------------------------------
// Phased SNN:
//   0) input_kernel : simulate 544 input LIF neurons once -> tr_in[t][i]
//      (spike flag recovered exactly as tr==1.0f)
//   1) hidden raster S (sequential over t, 1024 single-wave blocks, 4-deep
//      tr-row prefetch, register-resident w1 column + STDP clip)
//   2) pack S bits + zero tail rows of Sf
//   3) Gram G = S S^T (popcount, exact)
//   4) M_T via wave-parallel decay scans
//   5) A_T = (S @ w2_0)^T f32 GEMM (K-split x2)
//   6) output LIF recurrence: scatter-forward rank-1, triangular chunk-skip,
//      4-deep MT-row prefetch, 1024 single-wave blocks x 2 cols
// Valid because w2 is never clipped -> its evolution is linear in spikes.
// ---------------------------------------------------------------------------

#define DECAY_V  0.90483741803595952f   // exp(-1/10)
#define DECAY_TR 0.95122942450071403f   // exp(-1/20)
#define REST_F   (-70.0f)
#define RESET_F  (-65.0f)
#define THRESH_F (-55.0f)
#define ALPHA_F  (0.95f)
#define BETA_F   (0.8f)
#define NU1_PRE_F  (0.001f)
#define NU1_POST_F (0.01f)
#define NU2_F      (0.0001f)
#define GAIN_F     (20.0f)
#define LOG2D    (-0.072134752044448170f)  // log2(exp(-1/20))

static constexpr int IN_D  = 544;
static constexpr int HID_D = 1024;
static constexpr int OUT_D = 2048;
static constexpr int TMAX  = 512;

#define DP1  0.95122942450071403f
#define DP2  0.90483741803595957f
#define DP4  0.81873075307798186f
#define DP8  0.67032004603563930f
#define DP16 0.44932896411722159f
#define DP32 0.20189651799465541f

__device__ __forceinline__ float rdlane(float x, int l) {
    return __builtin_bit_cast(float,
        __builtin_amdgcn_readlane(__builtin_bit_cast(int, x), l));
}

template <int CTRL>
__device__ __forceinline__ float dpp_add(float x) {
    int y = __builtin_amdgcn_update_dpp(0, __builtin_bit_cast(int, x),
                                        CTRL, 0xF, 0xF, true);
    return x + __builtin_bit_cast(float, y);
}

__device__ __forceinline__ float wave_sum64(float x) {
    x = dpp_add<0xB1>(x);   // quad_perm [1,0,3,2]
    x = dpp_add<0x4E>(x);   // quad_perm [2,3,0,1]
    x = dpp_add<0x114>(x);  // row_shr:4
    x = dpp_add<0x118>(x);  // row_shr:8
    x = dpp_add<0x142>(x);  // row_bcast:15
    x = dpp_add<0x143>(x);  // row_bcast:31
    return rdlane(x, 63);
}

// ------------------- Phase 0: input LIF, simulated once --------------------
__global__ __launch_bounds__(64)
void input_kernel(const float* __restrict__ x, const int* __restrict__ Tp,
                  float* __restrict__ TR)
{
    const int i = blockIdx.x * 64 + threadIdx.x;
    if (i >= IN_D) return;
    const int T = Tp[0];
    const float cadd = REST_F * (1.0f - DECAY_V) + x[i] * GAIN_F;
    float v = REST_F, tr = 0.f;
    for (int t = 0; t < T; ++t) {
        const float vv = fmaf(DECAY_V, v, cadd);
        const bool sp = (vv >= THRESH_F);
        v  = sp ? RESET_F : vv;
        tr = sp ? 1.f : tr * DECAY_TR;      // tr==1.0f  <=>  spiked this step
        TR[(size_t)t * IN_D + i] = tr;
    }
}

// ------------------------- Phase 1: hidden raster --------------------------
__global__ __launch_bounds__(64)
void hidden_kernel(const float* __restrict__ w1, const float* __restrict__ TR,
                   const int* __restrict__ Tp, float* __restrict__ Sf)
{
    const int T = Tp[0];
    const int lane = threadIdx.x;
    const int col = blockIdx.x;              // 1024 blocks, one column each

    float w[9];
    #pragma unroll
    for (int k = 0; k < 9; ++k) {
        const int i = lane + 64 * k;
        w[k] = (i < IN_D) ? w1[(size_t)i * HID_D + col] : 0.f;
    }
    float v_h = 0.f, b_h = 0.f, tr_h = 0.f;

    auto prefetch = [&](float (&dst)[9], int row) {
        #pragma unroll
        for (int k = 0; k < 9; ++k) {
            const int i = lane + 64 * k;
            dst[k] = (i < IN_D) ? TR[(size_t)row * IN_D + i] : 0.f;
        }
    };
    auto step = [&](const float (&trc)[9], int t) {
        float acc = 0.f, s[9];
        #pragma unroll
        for (int k = 0; k < 9; ++k) {
            s[k] = (trc[k] == 1.0f) ? 1.f : 0.f;
            acc = fmaf(s[k], w[k], acc);     // same order as validated kernel
        }
        const float tot = wave_sum64(acc);
        const float vh2 = fmaf(ALPHA_F, v_h, tot);
        const bool hp = (vh2 >= 1.0f + b_h);
        const float sh = hp ? 1.f : 0.f;
        v_h  = hp ? 0.f : vh2;
        b_h  = fmaf(BETA_F, b_h, sh);
        tr_h = hp ? 1.f : tr_h * DECAY_TR;
        const float apot = hp ? NU1_POST_F : 0.f;
        const float adep = NU1_PRE_F * tr_h;
        #pragma unroll
        for (int k = 0; k < 9; ++k) {
            const float a  = fmaf(apot, trc[k], w[k]);
            const float nw = fmaf(-adep, s[k], a);
            w[k] = __builtin_amdgcn_fmed3f(nw, 0.f, 1.f);
        }
        if (lane == 0) Sf[(size_t)t * HID_D + col] = sh;
    };

    float B0[9], B1[9], B2[9], B3[9];
    prefetch(B0, 0);
    prefetch(B1, (1 < T) ? 1 : T - 1);
    prefetch(B2, (2 < T) ? 2 : T - 1);
    prefetch(B3, (3 < T) ? 3 : T - 1);
    for (int t = 0; t < T; t += 4) {
        step(B0, t);     if (t + 4 < T) prefetch(B0, t + 4);
        if (t + 1 >= T) break;
        step(B1, t + 1); if (t + 5 < T) prefetch(B1, t + 5);
        if (t + 2 >= T) break;
        step(B2, t + 2); if (t + 6 < T) prefetch(B2, t + 6);
        if (t + 3 >= T) break;
        step(B3, t + 3); if (t + 7 < T) prefetch(B3, t + 7);
    }
}

// ---------------- Phase 2: bit-pack S (+ zero tail rows) -------------------
__global__ void pack_kernel(float* __restrict__ Sf, const int* __restrict__ Tp,
                            unsigned long long* __restrict__ Sb)
{
    const int T = Tp[0];
    const int t = blockIdx.x;
    const int lane = threadIdx.x & 63, wv = threadIdx.x >> 6;
    if (t >= T) {
        ((float4*)(Sf + (size_t)t * HID_D))[threadIdx.x] = make_float4(0.f, 0.f, 0.f, 0.f);
        return;
    }
    #pragma unroll
    for (int q = 0; q < 4; ++q) {
        const int word = wv * 4 + q;
        const float s = Sf[(size_t)t * HID_D + word * 64 + lane];
        const unsigned long long m = __ballot(s > 0.5f);
        if (lane == 0) Sb[(size_t)t * 16 + word] = m;
    }
}

// ------------------------- Phase 3: Gram G = S S^T -------------------------
__global__ void gram_kernel(const unsigned long long* __restrict__ Sb,
                            const int* __restrict__ Tp, float* __restrict__ G)
{
    const int T = Tp[0];
    if ((int)blockIdx.x > (int)blockIdx.y) return;
    const int tid = threadIdx.x;
    __shared__ unsigned long long tR[16][17], uR[16][17];
    {
        const int r = tid >> 4, w = tid & 15;
        const int trow = blockIdx.y * 16 + r, urow = blockIdx.x * 16 + r;
        tR[r][w] = (trow < T) ? Sb[(size_t)trow * 16 + w] : 0ULL;
        uR[r][w] = (urow < T) ? Sb[(size_t)urow * 16 + w] : 0ULL;
    }
    __syncthreads();
    const int tx = tid & 15, ty = tid >> 4;
    const int t = blockIdx.y * 16 + ty, u = blockIdx.x * 16 + tx;
    if (t < T && u < t) {
        int s = 0;
        #pragma unroll
        for (int w = 0; w < 16; ++w) s += __popcll(tR[ty][w] & uR[tx][w]);
        G[(size_t)t * TMAX + u] = (float)s;
    }
}

// -------------- Phase 4: M_T columns via parallel decay scans --------------
__global__ __launch_bounds__(256)
void mt_kernel(const float* __restrict__ G, const int* __restrict__ Tp,
               float* __restrict__ MT)
{
    const int T = Tp[0];
    const int lane = threadIdx.x & 63;
    const int t = blockIdx.x * 4 + (threadIdx.x >> 6);
    if (t >= T) return;
    const float* Gr = G + (size_t)t * TMAX;
    const float dl1  = exp2f((float)(lane + 1) * LOG2D);
    const float d64l = exp2f((float)(64 - lane) * LOG2D);

    float g[8], kk[8];
    #pragma unroll
    for (int c = 0; c < 8; ++c) {
        const int tau = 64 * c + lane;
        g[c] = (tau < t) ? Gr[tau] : 0.f;
    }
    float kc = 0.f;
    #pragma unroll
    for (int c = 7; c >= 0; --c) {
        float k = g[c], u;
        u = __shfl_down(k, 1, 64);  if (lane < 63) k = fmaf(DP1, u, k);
        u = __shfl_down(k, 2, 64);  if (lane < 62) k = fmaf(DP2, u, k);
        u = __shfl_down(k, 4, 64);  if (lane < 60) k = fmaf(DP4, u, k);
        u = __shfl_down(k, 8, 64);  if (lane < 56) k = fmaf(DP8, u, k);
        u = __shfl_down(k, 16, 64); if (lane < 48) k = fmaf(DP16, u, k);
        u = __shfl_down(k, 32, 64); if (lane < 32) k = fmaf(DP32, u, k);
        k = fmaf(d64l, kc, k);
        kk[c] = k;
        kc = rdlane(k, 0);
    }
    float hc = 0.f;
    #pragma unroll
    for (int c = 0; c < 8; ++c) {
        float h = g[c], u;
        u = __shfl_up(h, 1, 64);  if (lane >= 1)  h = fmaf(DP1, u, h);
        u = __shfl_up(h, 2, 64);  if (lane >= 2)  h = fmaf(DP2, u, h);
        u = __shfl_up(h, 4, 64);  if (lane >= 4)  h = fmaf(DP4, u, h);
        u = __shfl_up(h, 8, 64);  if (lane >= 8)  h = fmaf(DP8, u, h);
        u = __shfl_up(h, 16, 64); if (lane >= 16) h = fmaf(DP16, u, h);
        u = __shfl_up(h, 32, 64); if (lane >= 32) h = fmaf(DP32, u, h);
        h = fmaf(dl1, hc, h);
        const int tau = 64 * c + lane;
        MT[(size_t)tau * TMAX + t] = (tau < t) ? (NU2_F * (h - kk[c])) : 0.f;
        hc = rdlane(h, 63);
    }
}

// ---------------- Phase 5: A_T = (S @ w2)^T, K-split GEMM ------------------
__global__ __launch_bounds__(256)
void gemm_kernel(const float* __restrict__ Sf, const float* __restrict__ w2,
                 float* __restrict__ AT, int klen)
{
    const int j0 = blockIdx.x * 128;
    const int t0 = blockIdx.y * 64;
    const int kbase = blockIdx.z * 512;
    float* ATp = AT + (size_t)blockIdx.z * OUT_D * TMAX;
    __shared__ float Ss[16][68];
    __shared__ float Ws[16][192];
    const int tid = threadIdx.x;
    const int sr = tid >> 2, sq = tid & 3;
    const int wq2 = tid & 31, wr2 = tid >> 5;
    const int wcol = (wq2 >> 1) * 12 + (wq2 & 1) * 4;
    const int tj = tid & 15, tt = tid >> 4;
    const int tjc = tj * 12;

    float acc[4][8];
    #pragma unroll
    for (int a = 0; a < 4; ++a)
        #pragma unroll
        for (int b = 0; b < 8; ++b) acc[a][b] = 0.f;

    for (int k0 = 0; k0 < klen; k0 += 16) {
        const float4 sv = *(const float4*)&Sf[(size_t)(t0 + sr) * HID_D + kbase + k0 + sq * 4];
        const float4 wa = *(const float4*)&w2[(size_t)(kbase + k0 + wr2) * OUT_D + j0 + wq2 * 4];
        const float4 wb = *(const float4*)&w2[(size_t)(kbase + k0 + wr2 + 8) * OUT_D + j0 + wq2 * 4];
        __syncthreads();
        Ss[sq * 4 + 0][sr] = sv.x;
        Ss[sq * 4 + 1][sr] = sv.y;
        Ss[sq * 4 + 2][sr] = sv.z;
        Ss[sq * 4 + 3][sr] = sv.w;
        *(float4*)&Ws[wr2][wcol] = wa;
        *(float4*)&Ws[wr2 + 8][wcol] = wb;
        __syncthreads();
        #pragma unroll
        for (int kk = 0; kk < 16; ++kk) {
            const float4 a4 = *(const float4*)&Ss[kk][tt * 4];
            const float4 b0 = *(const float4*)&Ws[kk][tjc];
            const float4 b1 = *(const float4*)&Ws[kk][tjc + 4];
            const float aa[4] = {a4.x, a4.y, a4.z, a4.w};
            const float bb[8] = {b0.x, b0.y, b0.z, b0.w, b1.x, b1.y, b1.z, b1.w};
            #pragma unroll
            for (int ti = 0; ti < 4; ++ti)
                #pragma unroll
                for (int jj = 0; jj < 8; ++jj)
                    acc[ti][jj] = fmaf(aa[ti], bb[jj], acc[ti][jj]);
        }
    }
    #pragma unroll
    for (int jj = 0; jj < 8; ++jj)
        *(float4*)&ATp[(size_t)(j0 + tj * 8 + jj) * TMAX + t0 + tt * 4] =
            make_float4(acc[0][jj], acc[1][jj], acc[2][jj], acc[3][jj]);
}

// ------------------- Phase 6: output recurrence (no barriers) --------------
template <int C>
__device__ __forceinline__ void rload_c(float (&R)[8], const float* __restrict__ MT,
                                        int t, int lane)
{
    #pragma unroll
    for (int k = C; k < 8; ++k) R[k] = MT[(size_t)t * TMAX + 64 * k + lane];
}

template <int C>
__device__ __forceinline__ void ostep(int t, int tt, const float (&R)[8],
                                      const float (&av)[2], float (&hs)[2][8],
                                      float (&v)[2], float* __restrict__ out,
                                      int j, int lane)
{
    float so[2];
    #pragma unroll
    for (int q = 0; q < 2; ++q) {
        const float iv = rdlane(av[q] + hs[q][C], tt);
        const float vd = fmaf(DECAY_V, v[q], REST_F * (1.0f - DECAY_V)) + iv;
        const bool sp = (vd >= THRESH_F);
        v[q]  = sp ? RESET_F : vd;
        so[q] = sp ? 1.f : 0.f;
    }
    if (lane == 0)
        *(float2*)&out[(size_t)t * OUT_D + j] = make_float2(so[0], so[1]);
    #pragma unroll
    for (int q = 0; q < 2; ++q)
        #pragma unroll
        for (int k = C; k < 8; ++k)
            hs[q][k] = fmaf(so[q], R[k], hs[q][k]);
}

template <int C>
__device__ __forceinline__ void chunk_body(const float* __restrict__ AT,
                                           const float* __restrict__ MT,
                                           float (&hs)[2][8], float (&v)[2],
                                           float* __restrict__ out, int j,
                                           int lane, int T, int nparts)
{
    constexpr int t0 = 64 * C;
    float av[2];
    #pragma unroll
    for (int q = 0; q < 2; ++q) {
        float a = AT[(size_t)(j + q) * TMAX + t0 + lane];
        if (nparts == 2) a += AT[(size_t)(OUT_D + j + q) * TMAX + t0 + lane];
        av[q] = a;
    }
    float R0[8], R1[8], R2[8], R3[8];
    rload_c<C>(R0, MT, t0 + 0, lane);
    rload_c<C>(R1, MT, t0 + 1, lane);
    rload_c<C>(R2, MT, t0 + 2, lane);
    rload_c<C>(R3, MT, t0 + 3, lane);
    #pragma unroll 1
    for (int tt = 0; tt < 64; tt += 4) {
        const int ta = t0 + tt;
        if (ta >= T) return;
        ostep<C>(ta, tt, R0, av, hs, v, out, j, lane);
        if (tt + 4 < 64) rload_c<C>(R0, MT, ta + 4, lane);
        if (ta + 1 >= T) return;
        ostep<C>(ta + 1, tt + 1, R1, av, hs, v, out, j, lane);
        if (tt + 5 < 64) rload_c<C>(R1, MT, ta + 5, lane);
        if (ta + 2 >= T) return;
        ostep<C>(ta + 2, tt + 2, R2, av, hs, v, out, j, lane);
        if (tt + 6 < 64) rload_c<C>(R2, MT, ta + 6, lane);
        if (ta + 3 >= T) return;
        ostep<C>(ta + 3, tt + 3, R3, av, hs, v, out, j, lane);
        if (tt + 7 < 64) rload_c<C>(R3, MT, ta + 7, lane);
    }
}

__global__ __launch_bounds__(64)
void out_kernel(const float* __restrict__ AT, const float* __restrict__ MT,
                const int* __restrict__ Tp, float* __restrict__ out, int nparts)
{
    const int T = Tp[0];
    const int lane = threadIdx.x;
    const int j = blockIdx.x * 2;            // 1024 blocks, 2 cols each
    float hs[2][8];
    #pragma unroll
    for (int q = 0; q < 2; ++q)
        #pragma unroll
        for (int k = 0; k < 8; ++k) hs[q][k] = 0.f;
    float v[2] = {REST_F, REST_F};

    chunk_body<0>(AT, MT, hs, v, out, j, lane, T, nparts);
    if (T >  64) chunk_body<1>(AT, MT, hs, v, out, j, lane, T, nparts);
    if (T > 128) chunk_body<2>(AT, MT, hs, v, out, j, lane, T, nparts);
    if (T > 192) chunk_body<3>(AT, MT, hs, v, out, j, lane, T, nparts);
    if (T > 256) chunk_body<4>(AT, MT, hs, v, out, j, lane, T, nparts);
    if (T > 320) chunk_body<5>(AT, MT, hs, v, out, j, lane, T, nparts);
    if (T > 384) chunk_body<6>(AT, MT, hs, v, out, j, lane, T, nparts);
    if (T > 448) chunk_body<7>(AT, MT, hs, v, out, j, lane, T, nparts);
}

extern "C" void kernel_launch(void* const* d_in, const int* in_sizes, int n_in,
                              void* d_out, int out_size, void* d_ws, size_t ws_size,
                              hipStream_t stream) {
    const float* x  = (const float*)d_in[0];
    const float* w1 = (const float*)d_in[1];
    const float* w2 = (const float*)d_in[2];
    const int*   Tp = (const int*)d_in[3];
    float* out = (float*)d_out;
    char* ws = (char*)d_ws;
    // layout: Sb 64K | G 1M | MT 1M | Sf 2M | TR 1.25M | AT 4M (or 8M K-split)
    unsigned long long* Sb = (unsigned long long*)(ws);
    float* G  = (float*)(ws + 65536);
    float* MT = (float*)(ws + 65536 + 1048576);
    float* Sf = (float*)(ws + 65536 + 2 * 1048576);
    float* TR = (float*)(ws + 65536 + 4 * 1048576);
    float* AT = (float*)(ws + 65536 + 4 * 1048576 + 1310720);
    const size_t base = 65536 + 4 * 1048576 + 1310720;
    const int nparts = (ws_size >= base + 2 * 4194304) ? 2 : 1;
    const int klen = (nparts == 2) ? 512 : 1024;

    hipLaunchKernelGGL(input_kernel,  dim3(9), dim3(64), 0, stream, x, Tp, TR);
    hipLaunchKernelGGL(hidden_kernel, dim3(1024), dim3(64), 0, stream, w1, TR, Tp, Sf);
    hipLaunchKernelGGL(pack_kernel,   dim3(TMAX), dim3(256), 0, stream, Sf, Tp, Sb);
    hipLaunchKernelGGL(gram_kernel,   dim3(32, 32), dim3(256), 0, stream, Sb, Tp, G);
    hipLaunchKernelGGL(mt_kernel,     dim3(128), dim3(256), 0, stream, G, Tp, MT);
    hipLaunchKernelGGL(gemm_kernel,   dim3(16, 8, nparts), dim3(256), 0, stream,
                       Sf, w2, AT, klen);
    hipLaunchKernelGGL(out_kernel,    dim3(1024), dim3(64), 0, stream, AT, MT, Tp, out, nparts);
}

// Round 5
// 355.925 us; speedup vs baseline: 1.2690x; 1.2690x over previous
//
#include <hip/hip_runtime.h>
#include <stdint.h>

// ---------------------------------------------------------------------------
// Phased SNN:
//   1) hidden raster S: 512 blocks x 64thr, 2 cols/wave, shared input-LIF sim
//      recomputed in-register (no global loads in the loop)
//   2) pack S bits + zero tail rows of Sf
//   3) Gram G = S S^T (popcount, exact)
//   4) M_T via wave-parallel decay scans
//   5) A_T = (S @ w2_0)^T f32 GEMM (K-split x2)
//   6) output LIF: per-64-chunk {LDS-staged in-chunk M tile -> cheap serial
//      loop} + batched cross-chunk GEMV (same accumulation order -> bitexact)
// Valid because w2 is never clipped -> its evolution is linear in spikes.
// ---------------------------------------------------------------------------

#define DECAY_V  0.90483741803595952f   // exp(-1/10)
#define DECAY_TR 0.95122942450071403f   // exp(-1/20)
#define REST_F   (-70.0f)
#define RESET_F  (-65.0f)
#define THRESH_F (-55.0f)
#define ALPHA_F  (0.95f)
#define BETA_F   (0.8f)
#define NU1_PRE_F  (0.001f)
#define NU1_POST_F (0.01f)
#define NU2_F      (0.0001f)
#define GAIN_F     (20.0f)
#define LOG2D    (-0.072134752044448170f)  // log2(exp(-1/20))

static constexpr int IN_D  = 544;
static constexpr int HID_D = 1024;
static constexpr int OUT_D = 2048;
static constexpr int TMAX  = 512;

#define DP1  0.95122942450071403f
#define DP2  0.90483741803595957f
#define DP4  0.81873075307798186f
#define DP8  0.67032004603563930f
#define DP16 0.44932896411722159f
#define DP32 0.20189651799465541f

__device__ __forceinline__ float rdlane(float x, int l) {
    return __builtin_bit_cast(float,
        __builtin_amdgcn_readlane(__builtin_bit_cast(int, x), l));
}

template <int CTRL>
__device__ __forceinline__ float dpp_add(float x) {
    int y = __builtin_amdgcn_update_dpp(0, __builtin_bit_cast(int, x),
                                        CTRL, 0xF, 0xF, true);
    return x + __builtin_bit_cast(float, y);
}

__device__ __forceinline__ float wave_sum64(float x) {
    x = dpp_add<0xB1>(x);   // quad_perm [1,0,3,2]
    x = dpp_add<0x4E>(x);   // quad_perm [2,3,0,1]
    x = dpp_add<0x114>(x);  // row_shr:4
    x = dpp_add<0x118>(x);  // row_shr:8
    x = dpp_add<0x142>(x);  // row_bcast:15
    x = dpp_add<0x143>(x);  // row_bcast:31
    return rdlane(x, 63);
}

// ------------- Phase 1: hidden raster, 2 columns per wave ------------------
__global__ __launch_bounds__(64)
void hidden_kernel(const float* __restrict__ x, const float* __restrict__ w1,
                   const int* __restrict__ Tp, float* __restrict__ Sf)
{
    const int T = Tp[0];
    const int lane = threadIdx.x;
    const int colA = blockIdx.x * 2;           // cols colA, colA+1
    const float c0 = REST_F * (1.0f - DECAY_V);

    float wA[9], wB[9], vi[9], tr[9], cadd[9];
    #pragma unroll
    for (int k = 0; k < 9; ++k) {
        const int i = lane + 64 * k;
        const bool ok = (i < IN_D);
        if (ok) {
            const float2 wv = *(const float2*)&w1[(size_t)i * HID_D + colA];
            wA[k] = wv.x; wB[k] = wv.y;
        } else { wA[k] = 0.f; wB[k] = 0.f; }
        cadd[k] = c0 + (ok ? x[i] * GAIN_F : 0.f);
        vi[k]   = REST_F;
        tr[k]   = 0.f;
    }
    float vhA = 0.f, bhA = 0.f, thA = 0.f;
    float vhB = 0.f, bhB = 0.f, thB = 0.f;

    for (int t = 0; t < T; ++t) {
        float accA = 0.f, accB = 0.f, s[9];
        #pragma unroll
        for (int k = 0; k < 9; ++k) {           // shared input LIF sim
            const float vv = fmaf(DECAY_V, vi[k], cadd[k]);
            const bool sp = (vv >= THRESH_F);
            vi[k] = sp ? RESET_F : vv;
            s[k]  = sp ? 1.f : 0.f;
            tr[k] = fmaxf(tr[k] * DECAY_TR, s[k]);   // == sp?1:tr*d (tr<=1)
            accA = fmaf(s[k], wA[k], accA);
            accB = fmaf(s[k], wB[k], accB);
        }
        const float totA = wave_sum64(accA);
        const float totB = wave_sum64(accB);
        // hidden RUM, col A
        const float vA2 = fmaf(ALPHA_F, vhA, totA);
        const bool hpA = (vA2 >= 1.0f + bhA);
        const float shA = hpA ? 1.f : 0.f;
        vhA = hpA ? 0.f : vA2;
        bhA = fmaf(BETA_F, bhA, shA);
        thA = hpA ? 1.f : thA * DECAY_TR;
        // hidden RUM, col B
        const float vB2 = fmaf(ALPHA_F, vhB, totB);
        const bool hpB = (vB2 >= 1.0f + bhB);
        const float shB = hpB ? 1.f : 0.f;
        vhB = hpB ? 0.f : vB2;
        bhB = fmaf(BETA_F, bhB, shB);
        thB = hpB ? 1.f : thB * DECAY_TR;
        // STDP on both columns
        const float apotA = hpA ? NU1_POST_F : 0.f;
        const float adepA = NU1_PRE_F * thA;
        const float apotB = hpB ? NU1_POST_F : 0.f;
        const float adepB = NU1_PRE_F * thB;
        #pragma unroll
        for (int k = 0; k < 9; ++k) {
            const float aA  = fmaf(apotA, tr[k], wA[k]);
            const float nwA = fmaf(-adepA, s[k], aA);
            wA[k] = __builtin_amdgcn_fmed3f(nwA, 0.f, 1.f);
            const float aB  = fmaf(apotB, tr[k], wB[k]);
            const float nwB = fmaf(-adepB, s[k], aB);
            wB[k] = __builtin_amdgcn_fmed3f(nwB, 0.f, 1.f);
        }
        if (lane == 0)
            *(float2*)&Sf[(size_t)t * HID_D + colA] = make_float2(shA, shB);
    }
}

// ---------------- Phase 2: bit-pack S (+ zero tail rows) -------------------
__global__ void pack_kernel(float* __restrict__ Sf, const int* __restrict__ Tp,
                            unsigned long long* __restrict__ Sb)
{
    const int T = Tp[0];
    const int t = blockIdx.x;
    const int lane = threadIdx.x & 63, wv = threadIdx.x >> 6;
    if (t >= T) {
        ((float4*)(Sf + (size_t)t * HID_D))[threadIdx.x] = make_float4(0.f, 0.f, 0.f, 0.f);
        return;
    }
    #pragma unroll
    for (int q = 0; q < 4; ++q) {
        const int word = wv * 4 + q;
        const float s = Sf[(size_t)t * HID_D + word * 64 + lane];
        const unsigned long long m = __ballot(s > 0.5f);
        if (lane == 0) Sb[(size_t)t * 16 + word] = m;
    }
}

// ------------------------- Phase 3: Gram G = S S^T -------------------------
__global__ void gram_kernel(const unsigned long long* __restrict__ Sb,
                            const int* __restrict__ Tp, float* __restrict__ G)
{
    const int T = Tp[0];
    if ((int)blockIdx.x > (int)blockIdx.y) return;
    const int tid = threadIdx.x;
    __shared__ unsigned long long tR[16][17], uR[16][17];
    {
        const int r = tid >> 4, w = tid & 15;
        const int trow = blockIdx.y * 16 + r, urow = blockIdx.x * 16 + r;
        tR[r][w] = (trow < T) ? Sb[(size_t)trow * 16 + w] : 0ULL;
        uR[r][w] = (urow < T) ? Sb[(size_t)urow * 16 + w] : 0ULL;
    }
    __syncthreads();
    const int tx = tid & 15, ty = tid >> 4;
    const int t = blockIdx.y * 16 + ty, u = blockIdx.x * 16 + tx;
    if (t < T && u < t) {
        int s = 0;
        #pragma unroll
        for (int w = 0; w < 16; ++w) s += __popcll(tR[ty][w] & uR[tx][w]);
        G[(size_t)t * TMAX + u] = (float)s;
    }
}

// -------------- Phase 4: M_T columns via parallel decay scans --------------
__global__ __launch_bounds__(256)
void mt_kernel(const float* __restrict__ G, const int* __restrict__ Tp,
               float* __restrict__ MT)
{
    const int T = Tp[0];
    const int lane = threadIdx.x & 63;
    const int t = blockIdx.x * 4 + (threadIdx.x >> 6);
    if (t >= TMAX) return;
    const int zstart = (t < T) ? t : 0;
    for (int tau = zstart; tau < TMAX; ++tau) MT[(size_t)tau * TMAX + t] = 0.f;
    if (t >= T) return;
    const float* Gr = G + (size_t)t * TMAX;
    const float dl1  = exp2f((float)(lane + 1) * LOG2D);
    const float d64l = exp2f((float)(64 - lane) * LOG2D);

    float g[8], kk[8];
    #pragma unroll
    for (int c = 0; c < 8; ++c) {
        const int tau = 64 * c + lane;
        g[c] = (tau < t) ? Gr[tau] : 0.f;
    }
    float kc = 0.f;
    #pragma unroll
    for (int c = 7; c >= 0; --c) {
        float k = g[c], u;
        u = __shfl_down(k, 1, 64);  if (lane < 63) k = fmaf(DP1, u, k);
        u = __shfl_down(k, 2, 64);  if (lane < 62) k = fmaf(DP2, u, k);
        u = __shfl_down(k, 4, 64);  if (lane < 60) k = fmaf(DP4, u, k);
        u = __shfl_down(k, 8, 64);  if (lane < 56) k = fmaf(DP8, u, k);
        u = __shfl_down(k, 16, 64); if (lane < 48) k = fmaf(DP16, u, k);
        u = __shfl_down(k, 32, 64); if (lane < 32) k = fmaf(DP32, u, k);
        k = fmaf(d64l, kc, k);
        kk[c] = k;
        kc = rdlane(k, 0);
    }
    float hc = 0.f;
    #pragma unroll
    for (int c = 0; c < 8; ++c) {
        float h = g[c], u;
        u = __shfl_up(h, 1, 64);  if (lane >= 1)  h = fmaf(DP1, u, h);
        u = __shfl_up(h, 2, 64);  if (lane >= 2)  h = fmaf(DP2, u, h);
        u = __shfl_up(h, 4, 64);  if (lane >= 4)  h = fmaf(DP4, u, h);
        u = __shfl_up(h, 8, 64);  if (lane >= 8)  h = fmaf(DP8, u, h);
        u = __shfl_up(h, 16, 64); if (lane >= 16) h = fmaf(DP16, u, h);
        u = __shfl_up(h, 32, 64); if (lane >= 32) h = fmaf(DP32, u, h);
        h = fmaf(dl1, hc, h);
        const int tau = 64 * c + lane;
        MT[(size_t)tau * TMAX + t] = (tau < t) ? (NU2_F * (h - kk[c])) : 0.f;
        hc = rdlane(h, 63);
    }
}

// ---------------- Phase 5: A_T = (S @ w2)^T, K-split GEMM ------------------
__global__ __launch_bounds__(256)
void gemm_kernel(const float* __restrict__ Sf, const float* __restrict__ w2,
                 float* __restrict__ AT, int klen)
{
    const int j0 = blockIdx.x * 128;
    const int t0 = blockIdx.y * 64;
    const int kbase = blockIdx.z * 512;
    float* ATp = AT + (size_t)blockIdx.z * OUT_D * TMAX;
    __shared__ float Ss[16][68];
    __shared__ float Ws[16][192];
    const int tid = threadIdx.x;
    const int sr = tid >> 2, sq = tid & 3;
    const int wq2 = tid & 31, wr2 = tid >> 5;
    const int wcol = (wq2 >> 1) * 12 + (wq2 & 1) * 4;
    const int tj = tid & 15, tt = tid >> 4;
    const int tjc = tj * 12;

    float acc[4][8];
    #pragma unroll
    for (int a = 0; a < 4; ++a)
        #pragma unroll
        for (int b = 0; b < 8; ++b) acc[a][b] = 0.f;

    for (int k0 = 0; k0 < klen; k0 += 16) {
        const float4 sv = *(const float4*)&Sf[(size_t)(t0 + sr) * HID_D + kbase + k0 + sq * 4];
        const float4 wa = *(const float4*)&w2[(size_t)(kbase + k0 + wr2) * OUT_D + j0 + wq2 * 4];
        const float4 wb = *(const float4*)&w2[(size_t)(kbase + k0 + wr2 + 8) * OUT_D + j0 + wq2 * 4];
        __syncthreads();
        Ss[sq * 4 + 0][sr] = sv.x;
        Ss[sq * 4 + 1][sr] = sv.y;
        Ss[sq * 4 + 2][sr] = sv.z;
        Ss[sq * 4 + 3][sr] = sv.w;
        *(float4*)&Ws[wr2][wcol] = wa;
        *(float4*)&Ws[wr2 + 8][wcol] = wb;
        __syncthreads();
        #pragma unroll
        for (int kk = 0; kk < 16; ++kk) {
            const float4 a4 = *(const float4*)&Ss[kk][tt * 4];
            const float4 b0 = *(const float4*)&Ws[kk][tjc];
            const float4 b1 = *(const float4*)&Ws[kk][tjc + 4];
            const float aa[4] = {a4.x, a4.y, a4.z, a4.w};
            const float bb[8] = {b0.x, b0.y, b0.z, b0.w, b1.x, b1.y, b1.z, b1.w};
            #pragma unroll
            for (int ti = 0; ti < 4; ++ti)
                #pragma unroll
                for (int jj = 0; jj < 8; ++jj)
                    acc[ti][jj] = fmaf(aa[ti], bb[jj], acc[ti][jj]);
        }
    }
    #pragma unroll
    for (int jj = 0; jj < 8; ++jj)
        *(float4*)&ATp[(size_t)(j0 + tj * 8 + jj) * TMAX + t0 + tt * 4] =
            make_float4(acc[0][jj], acc[1][jj], acc[2][jj], acc[3][jj]);
}

// -------------- Phase 6: output recurrence, chunked ------------------------
template <int C>
__device__ __forceinline__ void out_chunk(
    const float* __restrict__ AT, const float* __restrict__ MT,
    float (&hsA)[8], float (&hsB)[8], float& vA, float& vB,
    float* __restrict__ out, int j, int lane, int T, int nparts,
    float* __restrict__ LD, float2* __restrict__ so2)
{
    const int rem = T - 64 * C;
    const int mtv = (rem < 64) ? rem : 64;
    float avA = AT[(size_t)j * TMAX + 64 * C + lane];
    float avB = AT[(size_t)(j + 1) * TMAX + 64 * C + lane];
    if (nparts == 2) {
        avA += AT[(size_t)(OUT_D + j) * TMAX + 64 * C + lane];
        avB += AT[(size_t)(OUT_D + j + 1) * TMAX + 64 * C + lane];
    }
    const float* ldb = LD + (C & 1) * 4096;
    float accA = hsA[C], accB = hsB[C];
    // serial LIF over this chunk; lane l carries Min(64C+l, tau) rank-1 acc
    float mv0 = ldb[lane];
    float mv1 = (mtv > 1) ? ldb[64 + lane] : 0.f;
    for (int tt = 0; tt < mtv; ++tt) {
        const float mv = mv0;
        mv0 = mv1;
        if (tt + 2 < mtv) mv1 = ldb[(tt + 2) * 64 + lane];
        const float ivA = rdlane(avA + accA, tt);
        const float ivB = rdlane(avB + accB, tt);
        const float vdA = fmaf(DECAY_V, vA, REST_F * (1.0f - DECAY_V)) + ivA;
        const float vdB = fmaf(DECAY_V, vB, REST_F * (1.0f - DECAY_V)) + ivB;
        const bool spA = (vdA >= THRESH_F);
        const bool spB = (vdB >= THRESH_F);
        const float soA = spA ? 1.f : 0.f;
        const float soB = spB ? 1.f : 0.f;
        vA = spA ? RESET_F : vdA;
        vB = spB ? RESET_F : vdB;
        if (lane == 0)
            *(float2*)&out[(size_t)(64 * C + tt) * OUT_D + j] = make_float2(soA, soB);
        if (lane == tt) so2[tt] = make_float2(soA, soB);
        accA = fmaf(soA, mv, accA);
        accB = fmaf(soB, mv, accB);
    }
    if (C + 1 < 8 && 64 * (C + 1) < T) {
        // stage next chunk's 64x64 Min tile (batched, latency-tolerant)
        {
            float* dst = LD + ((C + 1) & 1) * 4096;
            const float* src = MT + (size_t)(64 * (C + 1)) * TMAX + 64 * (C + 1) + lane;
            #pragma unroll 16
            for (int r = 0; r < 64; ++r)
                dst[r * 64 + lane] = src[(size_t)r * TMAX];
        }
        // batched GEMV: scatter this chunk's spikes into future chunks' hs,
        // ascending tt per K -> same accumulation order as per-step rank-1
        for (int tt = 0; tt < mtv; ++tt) {
            const float2 s = so2[tt];
            const float* Mrow = MT + (size_t)(64 * C + tt) * TMAX + lane;
            #pragma unroll
            for (int K = C + 1; K < 8; ++K) {
                const float mval = Mrow[64 * K];
                hsA[K] = fmaf(s.x, mval, hsA[K]);
                hsB[K] = fmaf(s.y, mval, hsB[K]);
            }
        }
    }
}

__global__ __launch_bounds__(64)
void out_kernel(const float* __restrict__ AT, const float* __restrict__ MT,
                const int* __restrict__ Tp, float* __restrict__ out, int nparts)
{
    const int T = Tp[0];
    const int lane = threadIdx.x;
    const int j = blockIdx.x * 2;               // 1024 blocks, 2 cols each
    __shared__ float LD[2 * 4096];
    __shared__ float2 so2[64];

    float hsA[8], hsB[8];
    #pragma unroll
    for (int k = 0; k < 8; ++k) { hsA[k] = 0.f; hsB[k] = 0.f; }
    float vA = REST_F, vB = REST_F;

    // stage chunk 0
    {
        const float* src = MT + lane;
        #pragma unroll 16
        for (int r = 0; r < 64; ++r) LD[r * 64 + lane] = src[(size_t)r * TMAX];
    }
    out_chunk<0>(AT, MT, hsA, hsB, vA, vB, out, j, lane, T, nparts, LD, so2);
    if (T >  64) out_chunk<1>(AT, MT, hsA, hsB, vA, vB, out, j, lane, T, nparts, LD, so2);
    if (T > 128) out_chunk<2>(AT, MT, hsA, hsB, vA, vB, out, j, lane, T, nparts, LD, so2);
    if (T > 192) out_chunk<3>(AT, MT, hsA, hsB, vA, vB, out, j, lane, T, nparts, LD, so2);
    if (T > 256) out_chunk<4>(AT, MT, hsA, hsB, vA, vB, out, j, lane, T, nparts, LD, so2);
    if (T > 320) out_chunk<5>(AT, MT, hsA, hsB, vA, vB, out, j, lane, T, nparts, LD, so2);
    if (T > 384) out_chunk<6>(AT, MT, hsA, hsB, vA, vB, out, j, lane, T, nparts, LD, so2);
    if (T > 448) out_chunk<7>(AT, MT, hsA, hsB, vA, vB, out, j, lane, T, nparts, LD, so2);
}

extern "C" void kernel_launch(void* const* d_in, const int* in_sizes, int n_in,
                              void* d_out, int out_size, void* d_ws, size_t ws_size,
                              hipStream_t stream) {
    const float* x  = (const float*)d_in[0];
    const float* w1 = (const float*)d_in[1];
    const float* w2 = (const float*)d_in[2];
    const int*   Tp = (const int*)d_in[3];
    float* out = (float*)d_out;
    char* ws = (char*)d_ws;
    // layout: Sb 64K | G 1M | MT 1M | Sf 2M | AT 8M (K-split) or 4M
    unsigned long long* Sb = (unsigned long long*)(ws);
    float* G  = (float*)(ws + 65536);
    float* MT = (float*)(ws + 65536 + 1048576);
    float* Sf = (float*)(ws + 65536 + 2 * 1048576);
    float* AT = (float*)(ws + 65536 + 4 * 1048576);
    const size_t need2 = 65536 + 4 * 1048576 + 2 * 4194304;
    const int nparts = (ws_size >= need2) ? 2 : 1;
    const int klen = (nparts == 2) ? 512 : 1024;

    hipLaunchKernelGGL(hidden_kernel, dim3(HID_D / 2), dim3(64), 0, stream, x, w1, Tp, Sf);
    hipLaunchKernelGGL(pack_kernel,   dim3(TMAX), dim3(256), 0, stream, Sf, Tp, Sb);
    hipLaunchKernelGGL(gram_kernel,   dim3(32, 32), dim3(256), 0, stream, Sb, Tp, G);
    hipLaunchKernelGGL(mt_kernel,     dim3(128), dim3(256), 0, stream, G, Tp, MT);
    hipLaunchKernelGGL(gemm_kernel,   dim3(16, 8, nparts), dim3(256), 0, stream,
                       Sf, w2, AT, klen);
    hipLaunchKernelGGL(out_kernel,    dim3(OUT_D / 2), dim3(64), 0, stream, AT, MT, Tp, out, nparts);
}

// Round 6
// 335.744 us; speedup vs baseline: 1.3453x; 1.0601x over previous
//
#include <hip/hip_runtime.h>
#include <stdint.h>

// ---------------------------------------------------------------------------
// Phased SNN:
//   1) hidden raster S: 512 blocks x 256thr; wave = (column, input-half).
//      2 waves/column combine partials via LDS (1 barrier/step, parity dbuf);
//      2048 waves = 2/SIMD -> latency hidden. RUM duplicated per column-pair.
//   2) pack S bits + zero tail rows of Sf
//   3) Gram G = S S^T (popcount, exact)
//   4) M_T via wave-parallel decay scans
//   5) A_T = (S @ w2_0)^T f32 GEMM (K-split x2)
//   6) output LIF: per-64-chunk LDS-staged M tile + batched cross-chunk GEMV
// Valid because w2 is never clipped -> its evolution is linear in spikes.
// ---------------------------------------------------------------------------

#define DECAY_V  0.90483741803595952f   // exp(-1/10)
#define DECAY_TR 0.95122942450071403f   // exp(-1/20)
#define REST_F   (-70.0f)
#define RESET_F  (-65.0f)
#define THRESH_F (-55.0f)
#define ALPHA_F  (0.95f)
#define BETA_F   (0.8f)
#define NU1_PRE_F  (0.001f)
#define NU1_POST_F (0.01f)
#define NU2_F      (0.0001f)
#define GAIN_F     (20.0f)
#define LOG2D    (-0.072134752044448170f)  // log2(exp(-1/20))

static constexpr int IN_D  = 544;
static constexpr int HID_D = 1024;
static constexpr int OUT_D = 2048;
static constexpr int TMAX  = 512;

#define DP1  0.95122942450071403f
#define DP2  0.90483741803595957f
#define DP4  0.81873075307798186f
#define DP8  0.67032004603563930f
#define DP16 0.44932896411722159f
#define DP32 0.20189651799465541f

__device__ __forceinline__ float rdlane(float x, int l) {
    return __builtin_bit_cast(float,
        __builtin_amdgcn_readlane(__builtin_bit_cast(int, x), l));
}

template <int CTRL>
__device__ __forceinline__ float dpp_add(float x) {
    int y = __builtin_amdgcn_update_dpp(0, __builtin_bit_cast(int, x),
                                        CTRL, 0xF, 0xF, true);
    return x + __builtin_bit_cast(float, y);
}

__device__ __forceinline__ float wave_sum64(float x) {
    x = dpp_add<0xB1>(x);   // quad_perm [1,0,3,2]
    x = dpp_add<0x4E>(x);   // quad_perm [2,3,0,1]
    x = dpp_add<0x114>(x);  // row_shr:4
    x = dpp_add<0x118>(x);  // row_shr:8
    x = dpp_add<0x142>(x);  // row_bcast:15
    x = dpp_add<0x143>(x);  // row_bcast:31
    return rdlane(x, 63);
}

// -------- Phase 1: hidden raster, wave = (column, input-half) --------------
__global__ __launch_bounds__(256)
void hidden_kernel(const float* __restrict__ x, const float* __restrict__ w1,
                   const int* __restrict__ Tp, float* __restrict__ Sf)
{
    const int T = Tp[0];
    const int tid = threadIdx.x, lane = tid & 63, wv = tid >> 6;
    const int cp = wv >> 1;                  // 0/1 -> column within block
    const int h  = wv & 1;                   // input half: [272h, 272h+272)
    const int col = blockIdx.x * 2 + cp;
    const float c0 = REST_F * (1.0f - DECAY_V);
    __shared__ float part[2][4];             // [parity][wave]

    float w[5], vi[5], tr[5], cadd[5];
    #pragma unroll
    for (int k = 0; k < 5; ++k) {
        const int o = 64 * k + lane;         // offset within the half
        const int i = 272 * h + o;
        const bool ok = (o < 272);
        w[k]    = ok ? w1[(size_t)i * HID_D + col] : 0.f;
        cadd[k] = c0 + (ok ? x[i] * GAIN_F : 0.f);
        vi[k]   = REST_F;
        tr[k]   = 0.f;
    }
    float v_h = 0.f, b_h = 0.f, tr_h = 0.f;  // duplicated across the 2 waves

    for (int t = 0; t < T; ++t) {
        float acc = 0.f, s[5];
        #pragma unroll
        for (int k = 0; k < 5; ++k) {        // input LIF for this half
            const float vv = fmaf(DECAY_V, vi[k], cadd[k]);
            const bool sp = (vv >= THRESH_F);
            vi[k] = sp ? RESET_F : vv;
            s[k]  = sp ? 1.f : 0.f;
            tr[k] = fmaxf(tr[k] * DECAY_TR, s[k]);
            acc   = fmaf(s[k], w[k], acc);
        }
        const float p = wave_sum64(acc);
        const int par = t & 1;
        if (lane == 0) part[par][wv] = p;
        __syncthreads();
        const float tot = part[par][cp * 2] + part[par][cp * 2 + 1];
        // hidden RUM (identical in both waves of the column)
        const float vh2 = fmaf(ALPHA_F, v_h, tot);
        const bool hp = (vh2 >= 1.0f + b_h);
        const float sh = hp ? 1.f : 0.f;
        v_h  = hp ? 0.f : vh2;
        b_h  = fmaf(BETA_F, b_h, sh);
        tr_h = hp ? 1.f : tr_h * DECAY_TR;
        // STDP on this wave's 272 weights
        const float apot = hp ? NU1_POST_F : 0.f;
        const float adep = NU1_PRE_F * tr_h;
        #pragma unroll
        for (int k = 0; k < 5; ++k) {
            const float a  = fmaf(apot, tr[k], w[k]);
            const float nw = fmaf(-adep, s[k], a);
            w[k] = __builtin_amdgcn_fmed3f(nw, 0.f, 1.f);
        }
        if (h == 0 && lane == 0) Sf[(size_t)t * HID_D + col] = sh;
    }
}

// ---------------- Phase 2: bit-pack S (+ zero tail rows) -------------------
__global__ void pack_kernel(float* __restrict__ Sf, const int* __restrict__ Tp,
                            unsigned long long* __restrict__ Sb)
{
    const int T = Tp[0];
    const int t = blockIdx.x;
    const int lane = threadIdx.x & 63, wv = threadIdx.x >> 6;
    if (t >= T) {
        ((float4*)(Sf + (size_t)t * HID_D))[threadIdx.x] = make_float4(0.f, 0.f, 0.f, 0.f);
        return;
    }
    #pragma unroll
    for (int q = 0; q < 4; ++q) {
        const int word = wv * 4 + q;
        const float s = Sf[(size_t)t * HID_D + word * 64 + lane];
        const unsigned long long m = __ballot(s > 0.5f);
        if (lane == 0) Sb[(size_t)t * 16 + word] = m;
    }
}

// ------------------------- Phase 3: Gram G = S S^T -------------------------
__global__ void gram_kernel(const unsigned long long* __restrict__ Sb,
                            const int* __restrict__ Tp, float* __restrict__ G)
{
    const int T = Tp[0];
    if ((int)blockIdx.x > (int)blockIdx.y) return;
    const int tid = threadIdx.x;
    __shared__ unsigned long long tR[16][17], uR[16][17];
    {
        const int r = tid >> 4, w = tid & 15;
        const int trow = blockIdx.y * 16 + r, urow = blockIdx.x * 16 + r;
        tR[r][w] = (trow < T) ? Sb[(size_t)trow * 16 + w] : 0ULL;
        uR[r][w] = (urow < T) ? Sb[(size_t)urow * 16 + w] : 0ULL;
    }
    __syncthreads();
    const int tx = tid & 15, ty = tid >> 4;
    const int t = blockIdx.y * 16 + ty, u = blockIdx.x * 16 + tx;
    if (t < T && u < t) {
        int s = 0;
        #pragma unroll
        for (int w = 0; w < 16; ++w) s += __popcll(tR[ty][w] & uR[tx][w]);
        G[(size_t)t * TMAX + u] = (float)s;
    }
}

// -------------- Phase 4: M_T columns via parallel decay scans --------------
__global__ __launch_bounds__(256)
void mt_kernel(const float* __restrict__ G, const int* __restrict__ Tp,
               float* __restrict__ MT)
{
    const int T = Tp[0];
    const int lane = threadIdx.x & 63;
    const int t = blockIdx.x * 4 + (threadIdx.x >> 6);
    if (t >= TMAX) return;
    const int zstart = (t < T) ? t : 0;
    for (int tau = zstart; tau < TMAX; ++tau) MT[(size_t)tau * TMAX + t] = 0.f;
    if (t >= T) return;
    const float* Gr = G + (size_t)t * TMAX;
    const float dl1  = exp2f((float)(lane + 1) * LOG2D);
    const float d64l = exp2f((float)(64 - lane) * LOG2D);

    float g[8], kk[8];
    #pragma unroll
    for (int c = 0; c < 8; ++c) {
        const int tau = 64 * c + lane;
        g[c] = (tau < t) ? Gr[tau] : 0.f;
    }
    float kc = 0.f;
    #pragma unroll
    for (int c = 7; c >= 0; --c) {
        float k = g[c], u;
        u = __shfl_down(k, 1, 64);  if (lane < 63) k = fmaf(DP1, u, k);
        u = __shfl_down(k, 2, 64);  if (lane < 62) k = fmaf(DP2, u, k);
        u = __shfl_down(k, 4, 64);  if (lane < 60) k = fmaf(DP4, u, k);
        u = __shfl_down(k, 8, 64);  if (lane < 56) k = fmaf(DP8, u, k);
        u = __shfl_down(k, 16, 64); if (lane < 48) k = fmaf(DP16, u, k);
        u = __shfl_down(k, 32, 64); if (lane < 32) k = fmaf(DP32, u, k);
        k = fmaf(d64l, kc, k);
        kk[c] = k;
        kc = rdlane(k, 0);
    }
    float hc = 0.f;
    #pragma unroll
    for (int c = 0; c < 8; ++c) {
        float h = g[c], u;
        u = __shfl_up(h, 1, 64);  if (lane >= 1)  h = fmaf(DP1, u, h);
        u = __shfl_up(h, 2, 64);  if (lane >= 2)  h = fmaf(DP2, u, h);
        u = __shfl_up(h, 4, 64);  if (lane >= 4)  h = fmaf(DP4, u, h);
        u = __shfl_up(h, 8, 64);  if (lane >= 8)  h = fmaf(DP8, u, h);
        u = __shfl_up(h, 16, 64); if (lane >= 16) h = fmaf(DP16, u, h);
        u = __shfl_up(h, 32, 64); if (lane >= 32) h = fmaf(DP32, u, h);
        h = fmaf(dl1, hc, h);
        const int tau = 64 * c + lane;
        MT[(size_t)tau * TMAX + t] = (tau < t) ? (NU2_F * (h - kk[c])) : 0.f;
        hc = rdlane(h, 63);
    }
}

// ---------------- Phase 5: A_T = (S @ w2)^T, K-split GEMM ------------------
__global__ __launch_bounds__(256)
void gemm_kernel(const float* __restrict__ Sf, const float* __restrict__ w2,
                 float* __restrict__ AT, int klen)
{
    const int j0 = blockIdx.x * 128;
    const int t0 = blockIdx.y * 64;
    const int kbase = blockIdx.z * 512;
    float* ATp = AT + (size_t)blockIdx.z * OUT_D * TMAX;
    __shared__ float Ss[16][68];
    __shared__ float Ws[16][192];
    const int tid = threadIdx.x;
    const int sr = tid >> 2, sq = tid & 3;
    const int wq2 = tid & 31, wr2 = tid >> 5;
    const int wcol = (wq2 >> 1) * 12 + (wq2 & 1) * 4;
    const int tj = tid & 15, tt = tid >> 4;
    const int tjc = tj * 12;

    float acc[4][8];
    #pragma unroll
    for (int a = 0; a < 4; ++a)
        #pragma unroll
        for (int b = 0; b < 8; ++b) acc[a][b] = 0.f;

    for (int k0 = 0; k0 < klen; k0 += 16) {
        const float4 sv = *(const float4*)&Sf[(size_t)(t0 + sr) * HID_D + kbase + k0 + sq * 4];
        const float4 wa = *(const float4*)&w2[(size_t)(kbase + k0 + wr2) * OUT_D + j0 + wq2 * 4];
        const float4 wb = *(const float4*)&w2[(size_t)(kbase + k0 + wr2 + 8) * OUT_D + j0 + wq2 * 4];
        __syncthreads();
        Ss[sq * 4 + 0][sr] = sv.x;
        Ss[sq * 4 + 1][sr] = sv.y;
        Ss[sq * 4 + 2][sr] = sv.z;
        Ss[sq * 4 + 3][sr] = sv.w;
        *(float4*)&Ws[wr2][wcol] = wa;
        *(float4*)&Ws[wr2 + 8][wcol] = wb;
        __syncthreads();
        #pragma unroll
        for (int kk = 0; kk < 16; ++kk) {
            const float4 a4 = *(const float4*)&Ss[kk][tt * 4];
            const float4 b0 = *(const float4*)&Ws[kk][tjc];
            const float4 b1 = *(const float4*)&Ws[kk][tjc + 4];
            const float aa[4] = {a4.x, a4.y, a4.z, a4.w};
            const float bb[8] = {b0.x, b0.y, b0.z, b0.w, b1.x, b1.y, b1.z, b1.w};
            #pragma unroll
            for (int ti = 0; ti < 4; ++ti)
                #pragma unroll
                for (int jj = 0; jj < 8; ++jj)
                    acc[ti][jj] = fmaf(aa[ti], bb[jj], acc[ti][jj]);
        }
    }
    #pragma unroll
    for (int jj = 0; jj < 8; ++jj)
        *(float4*)&ATp[(size_t)(j0 + tj * 8 + jj) * TMAX + t0 + tt * 4] =
            make_float4(acc[0][jj], acc[1][jj], acc[2][jj], acc[3][jj]);
}

// -------------- Phase 6: output recurrence, chunked ------------------------
template <int C>
__device__ __forceinline__ void out_chunk(
    const float* __restrict__ AT, const float* __restrict__ MT,
    float (&hsA)[8], float (&hsB)[8], float& vA, float& vB,
    float* __restrict__ out, int j, int lane, int T, int nparts,
    float* __restrict__ LD, float2* __restrict__ so2)
{
    const int rem = T - 64 * C;
    const int mtv = (rem < 64) ? rem : 64;
    float avA = AT[(size_t)j * TMAX + 64 * C + lane];
    float avB = AT[(size_t)(j + 1) * TMAX + 64 * C + lane];
    if (nparts == 2) {
        avA += AT[(size_t)(OUT_D + j) * TMAX + 64 * C + lane];
        avB += AT[(size_t)(OUT_D + j + 1) * TMAX + 64 * C + lane];
    }
    const float* ldb = LD + (C & 1) * 4096;
    float accA = hsA[C], accB = hsB[C];
    float mv0 = ldb[lane];
    float mv1 = (mtv > 1) ? ldb[64 + lane] : 0.f;
    for (int tt = 0; tt < mtv; ++tt) {
        const float mv = mv0;
        mv0 = mv1;
        if (tt + 2 < mtv) mv1 = ldb[(tt + 2) * 64 + lane];
        const float ivA = rdlane(avA + accA, tt);
        const float ivB = rdlane(avB + accB, tt);
        const float vdA = fmaf(DECAY_V, vA, REST_F * (1.0f - DECAY_V)) + ivA;
        const float vdB = fmaf(DECAY_V, vB, REST_F * (1.0f - DECAY_V)) + ivB;
        const bool spA = (vdA >= THRESH_F);
        const bool spB = (vdB >= THRESH_F);
        const float soA = spA ? 1.f : 0.f;
        const float soB = spB ? 1.f : 0.f;
        vA = spA ? RESET_F : vdA;
        vB = spB ? RESET_F : vdB;
        if (lane == 0)
            *(float2*)&out[(size_t)(64 * C + tt) * OUT_D + j] = make_float2(soA, soB);
        if (lane == tt) so2[tt] = make_float2(soA, soB);
        accA = fmaf(soA, mv, accA);
        accB = fmaf(soB, mv, accB);
    }
    if (C + 1 < 8 && 64 * (C + 1) < T) {
        {
            float* dst = LD + ((C + 1) & 1) * 4096;
            const float* src = MT + (size_t)(64 * (C + 1)) * TMAX + 64 * (C + 1) + lane;
            #pragma unroll 16
            for (int r = 0; r < 64; ++r)
                dst[r * 64 + lane] = src[(size_t)r * TMAX];
        }
        for (int tt = 0; tt < mtv; ++tt) {
            const float2 s = so2[tt];
            const float* Mrow = MT + (size_t)(64 * C + tt) * TMAX + lane;
            #pragma unroll
            for (int K = C + 1; K < 8; ++K) {
                const float mval = Mrow[64 * K];
                hsA[K] = fmaf(s.x, mval, hsA[K]);
                hsB[K] = fmaf(s.y, mval, hsB[K]);
            }
        }
    }
}

__global__ __launch_bounds__(64)
void out_kernel(const float* __restrict__ AT, const float* __restrict__ MT,
                const int* __restrict__ Tp, float* __restrict__ out, int nparts)
{
    const int T = Tp[0];
    const int lane = threadIdx.x;
    const int j = blockIdx.x * 2;
    __shared__ float LD[2 * 4096];
    __shared__ float2 so2[64];

    float hsA[8], hsB[8];
    #pragma unroll
    for (int k = 0; k < 8; ++k) { hsA[k] = 0.f; hsB[k] = 0.f; }
    float vA = REST_F, vB = REST_F;

    {
        const float* src = MT + lane;
        #pragma unroll 16
        for (int r = 0; r < 64; ++r) LD[r * 64 + lane] = src[(size_t)r * TMAX];
    }
    out_chunk<0>(AT, MT, hsA, hsB, vA, vB, out, j, lane, T, nparts, LD, so2);
    if (T >  64) out_chunk<1>(AT, MT, hsA, hsB, vA, vB, out, j, lane, T, nparts, LD, so2);
    if (T > 128) out_chunk<2>(AT, MT, hsA, hsB, vA, vB, out, j, lane, T, nparts, LD, so2);
    if (T > 192) out_chunk<3>(AT, MT, hsA, hsB, vA, vB, out, j, lane, T, nparts, LD, so2);
    if (T > 256) out_chunk<4>(AT, MT, hsA, hsB, vA, vB, out, j, lane, T, nparts, LD, so2);
    if (T > 320) out_chunk<5>(AT, MT, hsA, hsB, vA, vB, out, j, lane, T, nparts, LD, so2);
    if (T > 384) out_chunk<6>(AT, MT, hsA, hsB, vA, vB, out, j, lane, T, nparts, LD, so2);
    if (T > 448) out_chunk<7>(AT, MT, hsA, hsB, vA, vB, out, j, lane, T, nparts, LD, so2);
}

extern "C" void kernel_launch(void* const* d_in, const int* in_sizes, int n_in,
                              void* d_out, int out_size, void* d_ws, size_t ws_size,
                              hipStream_t stream) {
    const float* x  = (const float*)d_in[0];
    const float* w1 = (const float*)d_in[1];
    const float* w2 = (const float*)d_in[2];
    const int*   Tp = (const int*)d_in[3];
    float* out = (float*)d_out;
    char* ws = (char*)d_ws;
    // layout: Sb 64K | G 1M | MT 1M | Sf 2M | AT 8M (K-split) or 4M
    unsigned long long* Sb = (unsigned long long*)(ws);
    float* G  = (float*)(ws + 65536);
    float* MT = (float*)(ws + 65536 + 1048576);
    float* Sf = (float*)(ws + 65536 + 2 * 1048576);
    float* AT = (float*)(ws + 65536 + 4 * 1048576);
    const size_t need2 = 65536 + 4 * 1048576 + 2 * 4194304;
    const int nparts = (ws_size >= need2) ? 2 : 1;
    const int klen = (nparts == 2) ? 512 : 1024;

    hipLaunchKernelGGL(hidden_kernel, dim3(HID_D / 2), dim3(256), 0, stream, x, w1, Tp, Sf);
    hipLaunchKernelGGL(pack_kernel,   dim3(TMAX), dim3(256), 0, stream, Sf, Tp, Sb);
    hipLaunchKernelGGL(gram_kernel,   dim3(32, 32), dim3(256), 0, stream, Sb, Tp, G);
    hipLaunchKernelGGL(mt_kernel,     dim3(128), dim3(256), 0, stream, G, Tp, MT);
    hipLaunchKernelGGL(gemm_kernel,   dim3(16, 8, nparts), dim3(256), 0, stream,
                       Sf, w2, AT, klen);
    hipLaunchKernelGGL(out_kernel,    dim3(OUT_D / 2), dim3(64), 0, stream, AT, MT, Tp, out, nparts);
}

// Round 7
// 321.550 us; speedup vs baseline: 1.4047x; 1.0441x over previous
//
#include <hip/hip_runtime.h>
#include <stdint.h>

// ---------------------------------------------------------------------------
// Phased SNN:
//   1) hidden raster S: 512 blocks x 256thr; wave = (column, input-half).
//      2 waves/column combine partials via LDS (1 barrier/step, parity dbuf).
//      __launch_bounds__(256,2): 256-VGPR cap -> no scratch spills (r6 bug).
//   2) pack S bits + zero tail rows of Sf
//   3) Gram G = S S^T (popcount, exact)
//   4) M_T via wave-parallel decay scans (writes only tau<t, t<T; consumers
//      mask the diagonal tile and never read the unwritten region)
//   5) A_T = (S @ w2_0)^T f32 GEMM (K-split x2)
//   6) output LIF: per-64-chunk LDS-staged M tile + batched cross-chunk GEMV
// Valid because w2 is never clipped -> its evolution is linear in spikes.
// ---------------------------------------------------------------------------

#define DECAY_V  0.90483741803595952f   // exp(-1/10)
#define DECAY_TR 0.95122942450071403f   // exp(-1/20)
#define REST_F   (-70.0f)
#define RESET_F  (-65.0f)
#define THRESH_F (-55.0f)
#define ALPHA_F  (0.95f)
#define BETA_F   (0.8f)
#define NU1_PRE_F  (0.001f)
#define NU1_POST_F (0.01f)
#define NU2_F      (0.0001f)
#define GAIN_F     (20.0f)
#define LOG2D    (-0.072134752044448170f)  // log2(exp(-1/20))

static constexpr int IN_D  = 544;
static constexpr int HID_D = 1024;
static constexpr int OUT_D = 2048;
static constexpr int TMAX  = 512;

#define DP1  0.95122942450071403f
#define DP2  0.90483741803595957f
#define DP4  0.81873075307798186f
#define DP8  0.67032004603563930f
#define DP16 0.44932896411722159f
#define DP32 0.20189651799465541f

__device__ __forceinline__ float rdlane(float x, int l) {
    return __builtin_bit_cast(float,
        __builtin_amdgcn_readlane(__builtin_bit_cast(int, x), l));
}

template <int CTRL>
__device__ __forceinline__ float dpp_add(float x) {
    int y = __builtin_amdgcn_update_dpp(0, __builtin_bit_cast(int, x),
                                        CTRL, 0xF, 0xF, true);
    return x + __builtin_bit_cast(float, y);
}

__device__ __forceinline__ float wave_sum64(float x) {
    x = dpp_add<0xB1>(x);   // quad_perm [1,0,3,2]
    x = dpp_add<0x4E>(x);   // quad_perm [2,3,0,1]
    x = dpp_add<0x114>(x);  // row_shr:4
    x = dpp_add<0x118>(x);  // row_shr:8
    x = dpp_add<0x142>(x);  // row_bcast:15
    x = dpp_add<0x143>(x);  // row_bcast:31
    return rdlane(x, 63);
}

// -------- Phase 1: hidden raster, wave = (column, input-half) --------------
__global__ __launch_bounds__(256, 2)
void hidden_kernel(const float* __restrict__ x, const float* __restrict__ w1,
                   const int* __restrict__ Tp, float* __restrict__ Sf)
{
    const int T = Tp[0];
    const int tid = threadIdx.x, lane = tid & 63, wv = tid >> 6;
    const int cp = wv >> 1;                  // 0/1 -> column within block
    const int h  = wv & 1;                   // input half: [272h, 272h+272)
    const int col = blockIdx.x * 2 + cp;
    const float c0 = REST_F * (1.0f - DECAY_V);
    __shared__ float part[2][4];             // [parity][wave]

    float w[5], vi[5], tr[5], cadd[5];
    #pragma unroll
    for (int k = 0; k < 5; ++k) {
        const int o = 64 * k + lane;         // offset within the half
        const int i = 272 * h + o;
        const bool ok = (o < 272);
        w[k]    = ok ? w1[(size_t)i * HID_D + col] : 0.f;
        cadd[k] = c0 + (ok ? x[i] * GAIN_F : 0.f);
        vi[k]   = REST_F;
        tr[k]   = 0.f;
    }
    float v_h = 0.f, b_h = 0.f, tr_h = 0.f;  // duplicated across the 2 waves

    for (int t = 0; t < T; ++t) {
        float acc = 0.f, s[5];
        #pragma unroll
        for (int k = 0; k < 5; ++k) {        // input LIF for this half
            const float vv = fmaf(DECAY_V, vi[k], cadd[k]);
            const bool sp = (vv >= THRESH_F);
            vi[k] = sp ? RESET_F : vv;
            s[k]  = sp ? 1.f : 0.f;
            tr[k] = fmaxf(tr[k] * DECAY_TR, s[k]);
            acc   = fmaf(s[k], w[k], acc);
        }
        const float p = wave_sum64(acc);
        const int par = t & 1;
        if (lane == 0) part[par][wv] = p;
        __syncthreads();
        const float tot = p + part[par][wv ^ 1];   // commutative -> bitexact
        // hidden RUM (identical in both waves of the column)
        const float vh2 = fmaf(ALPHA_F, v_h, tot);
        const bool hp = (vh2 >= 1.0f + b_h);
        const float sh = hp ? 1.f : 0.f;
        v_h  = hp ? 0.f : vh2;
        b_h  = fmaf(BETA_F, b_h, sh);
        tr_h = hp ? 1.f : tr_h * DECAY_TR;
        // STDP on this wave's 272 weights
        const float apot = hp ? NU1_POST_F : 0.f;
        const float adep = NU1_PRE_F * tr_h;
        #pragma unroll
        for (int k = 0; k < 5; ++k) {
            const float a  = fmaf(apot, tr[k], w[k]);
            const float nw = fmaf(-adep, s[k], a);
            w[k] = __builtin_amdgcn_fmed3f(nw, 0.f, 1.f);
        }
        if (h == 0 && lane == 0) Sf[(size_t)t * HID_D + col] = sh;
    }
}

// ---------------- Phase 2: bit-pack S (+ zero tail rows) -------------------
__global__ void pack_kernel(float* __restrict__ Sf, const int* __restrict__ Tp,
                            unsigned long long* __restrict__ Sb)
{
    const int T = Tp[0];
    const int t = blockIdx.x;
    const int lane = threadIdx.x & 63, wv = threadIdx.x >> 6;
    if (t >= T) {
        ((float4*)(Sf + (size_t)t * HID_D))[threadIdx.x] = make_float4(0.f, 0.f, 0.f, 0.f);
        return;
    }
    #pragma unroll
    for (int q = 0; q < 4; ++q) {
        const int word = wv * 4 + q;
        const float s = Sf[(size_t)t * HID_D + word * 64 + lane];
        const unsigned long long m = __ballot(s > 0.5f);
        if (lane == 0) Sb[(size_t)t * 16 + word] = m;
    }
}

// ------------------------- Phase 3: Gram G = S S^T -------------------------
__global__ void gram_kernel(const unsigned long long* __restrict__ Sb,
                            const int* __restrict__ Tp, float* __restrict__ G)
{
    const int T = Tp[0];
    if ((int)blockIdx.x > (int)blockIdx.y) return;
    const int tid = threadIdx.x;
    __shared__ unsigned long long tR[16][17], uR[16][17];
    {
        const int r = tid >> 4, w = tid & 15;
        const int trow = blockIdx.y * 16 + r, urow = blockIdx.x * 16 + r;
        tR[r][w] = (trow < T) ? Sb[(size_t)trow * 16 + w] : 0ULL;
        uR[r][w] = (urow < T) ? Sb[(size_t)urow * 16 + w] : 0ULL;
    }
    __syncthreads();
    const int tx = tid & 15, ty = tid >> 4;
    const int t = blockIdx.y * 16 + ty, u = blockIdx.x * 16 + tx;
    if (t < T && u < t) {
        int s = 0;
        #pragma unroll
        for (int w = 0; w < 16; ++w) s += __popcll(tR[ty][w] & uR[tx][w]);
        G[(size_t)t * TMAX + u] = (float)s;
    }
}

// -------------- Phase 4: M_T columns via parallel decay scans --------------
// Writes only MT[tau][t] for tau < t, t < T. Unwritten region is never read.
__global__ __launch_bounds__(256)
void mt_kernel(const float* __restrict__ G, const int* __restrict__ Tp,
               float* __restrict__ MT)
{
    const int T = Tp[0];
    const int lane = threadIdx.x & 63;
    const int t = blockIdx.x * 4 + (threadIdx.x >> 6);
    if (t >= T) return;
    const float* Gr = G + (size_t)t * TMAX;
    const float dl1  = exp2f((float)(lane + 1) * LOG2D);
    const float d64l = exp2f((float)(64 - lane) * LOG2D);

    float g[8], kk[8];
    #pragma unroll
    for (int c = 0; c < 8; ++c) {
        const int tau = 64 * c + lane;
        g[c] = (tau < t) ? Gr[tau] : 0.f;
    }
    float kc = 0.f;
    #pragma unroll
    for (int c = 7; c >= 0; --c) {
        float k = g[c], u;
        u = __shfl_down(k, 1, 64);  if (lane < 63) k = fmaf(DP1, u, k);
        u = __shfl_down(k, 2, 64);  if (lane < 62) k = fmaf(DP2, u, k);
        u = __shfl_down(k, 4, 64);  if (lane < 60) k = fmaf(DP4, u, k);
        u = __shfl_down(k, 8, 64);  if (lane < 56) k = fmaf(DP8, u, k);
        u = __shfl_down(k, 16, 64); if (lane < 48) k = fmaf(DP16, u, k);
        u = __shfl_down(k, 32, 64); if (lane < 32) k = fmaf(DP32, u, k);
        k = fmaf(d64l, kc, k);
        kk[c] = k;
        kc = rdlane(k, 0);
    }
    float hc = 0.f;
    #pragma unroll
    for (int c = 0; c < 8; ++c) {
        float h = g[c], u;
        u = __shfl_up(h, 1, 64);  if (lane >= 1)  h = fmaf(DP1, u, h);
        u = __shfl_up(h, 2, 64);  if (lane >= 2)  h = fmaf(DP2, u, h);
        u = __shfl_up(h, 4, 64);  if (lane >= 4)  h = fmaf(DP4, u, h);
        u = __shfl_up(h, 8, 64);  if (lane >= 8)  h = fmaf(DP8, u, h);
        u = __shfl_up(h, 16, 64); if (lane >= 16) h = fmaf(DP16, u, h);
        u = __shfl_up(h, 32, 64); if (lane >= 32) h = fmaf(DP32, u, h);
        h = fmaf(dl1, hc, h);
        const int tau = 64 * c + lane;
        if (tau < t) MT[(size_t)tau * TMAX + t] = NU2_F * (h - kk[c]);
        hc = rdlane(h, 63);
    }
}

// ---------------- Phase 5: A_T = (S @ w2)^T, K-split GEMM ------------------
__global__ __launch_bounds__(256)
void gemm_kernel(const float* __restrict__ Sf, const float* __restrict__ w2,
                 float* __restrict__ AT, int klen)
{
    const int j0 = blockIdx.x * 128;
    const int t0 = blockIdx.y * 64;
    const int kbase = blockIdx.z * 512;
    float* ATp = AT + (size_t)blockIdx.z * OUT_D * TMAX;
    __shared__ float Ss[16][68];
    __shared__ float Ws[16][192];
    const int tid = threadIdx.x;
    const int sr = tid >> 2, sq = tid & 3;
    const int wq2 = tid & 31, wr2 = tid >> 5;
    const int wcol = (wq2 >> 1) * 12 + (wq2 & 1) * 4;
    const int tj = tid & 15, tt = tid >> 4;
    const int tjc = tj * 12;

    float acc[4][8];
    #pragma unroll
    for (int a = 0; a < 4; ++a)
        #pragma unroll
        for (int b = 0; b < 8; ++b) acc[a][b] = 0.f;

    for (int k0 = 0; k0 < klen; k0 += 16) {
        const float4 sv = *(const float4*)&Sf[(size_t)(t0 + sr) * HID_D + kbase + k0 + sq * 4];
        const float4 wa = *(const float4*)&w2[(size_t)(kbase + k0 + wr2) * OUT_D + j0 + wq2 * 4];
        const float4 wb = *(const float4*)&w2[(size_t)(kbase + k0 + wr2 + 8) * OUT_D + j0 + wq2 * 4];
        __syncthreads();
        Ss[sq * 4 + 0][sr] = sv.x;
        Ss[sq * 4 + 1][sr] = sv.y;
        Ss[sq * 4 + 2][sr] = sv.z;
        Ss[sq * 4 + 3][sr] = sv.w;
        *(float4*)&Ws[wr2][wcol] = wa;
        *(float4*)&Ws[wr2 + 8][wcol] = wb;
        __syncthreads();
        #pragma unroll
        for (int kk = 0; kk < 16; ++kk) {
            const float4 a4 = *(const float4*)&Ss[kk][tt * 4];
            const float4 b0 = *(const float4*)&Ws[kk][tjc];
            const float4 b1 = *(const float4*)&Ws[kk][tjc + 4];
            const float aa[4] = {a4.x, a4.y, a4.z, a4.w};
            const float bb[8] = {b0.x, b0.y, b0.z, b0.w, b1.x, b1.y, b1.z, b1.w};
            #pragma unroll
            for (int ti = 0; ti < 4; ++ti)
                #pragma unroll
                for (int jj = 0; jj < 8; ++jj)
                    acc[ti][jj] = fmaf(aa[ti], bb[jj], acc[ti][jj]);
        }
    }
    #pragma unroll
    for (int jj = 0; jj < 8; ++jj)
        *(float4*)&AT[(size_t)blockIdx.z * OUT_D * TMAX +
                      (size_t)(j0 + tj * 8 + jj) * TMAX + t0 + tt * 4] =
            make_float4(acc[0][jj], acc[1][jj], acc[2][jj], acc[3][jj]);
    (void)ATp;
}

// -------------- Phase 6: output recurrence, chunked ------------------------
// Diagonal 64x64 tile staged with (r < lane) mask => upper triangle is 0
// without requiring MT's unwritten region to be zeroed.
template <int C>
__device__ __forceinline__ void out_chunk(
    const float* __restrict__ AT, const float* __restrict__ MT,
    float (&hsA)[8], float (&hsB)[8], float& vA, float& vB,
    float* __restrict__ out, int j, int lane, int T, int nparts,
    float* __restrict__ LD, float2* __restrict__ so2)
{
    const int rem = T - 64 * C;
    const int mtv = (rem < 64) ? rem : 64;
    float avA = AT[(size_t)j * TMAX + 64 * C + lane];
    float avB = AT[(size_t)(j + 1) * TMAX + 64 * C + lane];
    if (nparts == 2) {
        avA += AT[(size_t)(OUT_D + j) * TMAX + 64 * C + lane];
        avB += AT[(size_t)(OUT_D + j + 1) * TMAX + 64 * C + lane];
    }
    const float* ldb = LD + (C & 1) * 4096;
    float accA = hsA[C], accB = hsB[C];
    float mv0 = ldb[lane];
    float mv1 = (mtv > 1) ? ldb[64 + lane] : 0.f;
    for (int tt = 0; tt < mtv; ++tt) {
        const float mv = mv0;
        mv0 = mv1;
        if (tt + 2 < mtv) mv1 = ldb[(tt + 2) * 64 + lane];
        const float ivA = rdlane(avA + accA, tt);
        const float ivB = rdlane(avB + accB, tt);
        const float vdA = fmaf(DECAY_V, vA, REST_F * (1.0f - DECAY_V)) + ivA;
        const float vdB = fmaf(DECAY_V, vB, REST_F * (1.0f - DECAY_V)) + ivB;
        const bool spA = (vdA >= THRESH_F);
        const bool spB = (vdB >= THRESH_F);
        const float soA = spA ? 1.f : 0.f;
        const float soB = spB ? 1.f : 0.f;
        vA = spA ? RESET_F : vdA;
        vB = spB ? RESET_F : vdB;
        if (lane == 0)
            *(float2*)&out[(size_t)(64 * C + tt) * OUT_D + j] = make_float2(soA, soB);
        if (lane == tt) so2[tt] = make_float2(soA, soB);
        accA = fmaf(soA, mv, accA);
        accB = fmaf(soB, mv, accB);
    }
    if (C + 1 < 8 && 64 * (C + 1) < T) {
        {
            float* dst = LD + ((C + 1) & 1) * 4096;
            const float* src = MT + (size_t)(64 * (C + 1)) * TMAX + 64 * (C + 1) + lane;
            #pragma unroll 16
            for (int r = 0; r < 64; ++r) {
                const float v = src[(size_t)r * TMAX];
                dst[r * 64 + lane] = (r < lane) ? v : 0.f;   // tau<t mask
            }
        }
        for (int tt = 0; tt < mtv; ++tt) {
            const float2 s = so2[tt];
            const float* Mrow = MT + (size_t)(64 * C + tt) * TMAX + lane;
            #pragma unroll
            for (int K = C + 1; K < 8; ++K) {
                const float mval = Mrow[64 * K];
                hsA[K] = fmaf(s.x, mval, hsA[K]);
                hsB[K] = fmaf(s.y, mval, hsB[K]);
            }
        }
    }
}

__global__ __launch_bounds__(64, 2)
void out_kernel(const float* __restrict__ AT, const float* __restrict__ MT,
                const int* __restrict__ Tp, float* __restrict__ out, int nparts)
{
    const int T = Tp[0];
    const int lane = threadIdx.x;
    const int j = blockIdx.x * 2;
    __shared__ float LD[2 * 4096];
    __shared__ float2 so2[64];

    float hsA[8], hsB[8];
    #pragma unroll
    for (int k = 0; k < 8; ++k) { hsA[k] = 0.f; hsB[k] = 0.f; }
    float vA = REST_F, vB = REST_F;

    {
        const float* src = MT + lane;
        #pragma unroll 16
        for (int r = 0; r < 64; ++r) {
            const float v = src[(size_t)r * TMAX];
            LD[r * 64 + lane] = (r < lane) ? v : 0.f;        // tau<t mask
        }
    }
    out_chunk<0>(AT, MT, hsA, hsB, vA, vB, out, j, lane, T, nparts, LD, so2);
    if (T >  64) out_chunk<1>(AT, MT, hsA, hsB, vA, vB, out, j, lane, T, nparts, LD, so2);
    if (T > 128) out_chunk<2>(AT, MT, hsA, hsB, vA, vB, out, j, lane, T, nparts, LD, so2);
    if (T > 192) out_chunk<3>(AT, MT, hsA, hsB, vA, vB, out, j, lane, T, nparts, LD, so2);
    if (T > 256) out_chunk<4>(AT, MT, hsA, hsB, vA, vB, out, j, lane, T, nparts, LD, so2);
    if (T > 320) out_chunk<5>(AT, MT, hsA, hsB, vA, vB, out, j, lane, T, nparts, LD, so2);
    if (T > 384) out_chunk<6>(AT, MT, hsA, hsB, vA, vB, out, j, lane, T, nparts, LD, so2);
    if (T > 448) out_chunk<7>(AT, MT, hsA, hsB, vA, vB, out, j, lane, T, nparts, LD, so2);
}

extern "C" void kernel_launch(void* const* d_in, const int* in_sizes, int n_in,
                              void* d_out, int out_size, void* d_ws, size_t ws_size,
                              hipStream_t stream) {
    const float* x  = (const float*)d_in[0];
    const float* w1 = (const float*)d_in[1];
    const float* w2 = (const float*)d_in[2];
    const int*   Tp = (const int*)d_in[3];
    float* out = (float*)d_out;
    char* ws = (char*)d_ws;
    // layout: Sb 64K | G 1M | MT 1M | Sf 2M | AT 8M (K-split) or 4M
    unsigned long long* Sb = (unsigned long long*)(ws);
    float* G  = (float*)(ws + 65536);
    float* MT = (float*)(ws + 65536 + 1048576);
    float* Sf = (float*)(ws + 65536 + 2 * 1048576);
    float* AT = (float*)(ws + 65536 + 4 * 1048576);
    const size_t need2 = 65536 + 4 * 1048576 + 2 * 4194304;
    const int nparts = (ws_size >= need2) ? 2 : 1;
    const int klen = (nparts == 2) ? 512 : 1024;

    hipLaunchKernelGGL(hidden_kernel, dim3(HID_D / 2), dim3(256), 0, stream, x, w1, Tp, Sf);
    hipLaunchKernelGGL(pack_kernel,   dim3(TMAX), dim3(256), 0, stream, Sf, Tp, Sb);
    hipLaunchKernelGGL(gram_kernel,   dim3(32, 32), dim3(256), 0, stream, Sb, Tp, G);
    hipLaunchKernelGGL(mt_kernel,     dim3(128), dim3(256), 0, stream, G, Tp, MT);
    hipLaunchKernelGGL(gemm_kernel,   dim3(16, 8, nparts), dim3(256), 0, stream,
                       Sf, w2, AT, klen);
    hipLaunchKernelGGL(out_kernel,    dim3(OUT_D / 2), dim3(64), 0, stream, AT, MT, Tp, out, nparts);
}